// Round 7
// baseline (3099.435 us; speedup 1.0000x reference)
//
#include <hip/hip_runtime.h>
#include <hip/hip_bf16.h>
#include <math.h>

#define BB 64
#define TT 256
#define LCH 16
#define DC 50
#define CHN 100
#define DW 300
#define DF 20
#define HID 256
#define G4 1024
#define INDIM 420
#define NTAG 52
#define TSTART 50
#define TSTOP 51

// ------------------- workspace layout (bytes) -------------------
static constexpr size_t OFF_POOL  = 0;                       // 6,553,600
static constexpr size_t OFF_X     = 6553600;                 // 27,525,120 -> end 34,078,720
static constexpr size_t OFF_HF    = 0;                       // 16,777,216 (overlaps pooled+x, dead by then)
static constexpr size_t OFF_HB    = 16777216;                // 16,777,216 -> 33,554,432
static constexpr size_t OFF_XSF   = 34078720;                // 67,108,864
static constexpr size_t OFF_XSB   = 101187584;               // 67,108,864 -> 168,296,448
static constexpr size_t OFF_FEATS = 168296448;               // 3,407,872  -> 171,704,320
static constexpr size_t OFF_WPF   = 171704320;               // 512 KB used (fp16, 262144 elems)
static constexpr size_t OFF_WPB   = 172752896;               // 512 KB used (fp16, 262144 elems)
static constexpr size_t OFF_LOSSB = 173801472;               // 256

typedef _Float16 v2h __attribute__((ext_vector_type(2)));
union UH2 { unsigned u; v2h h; };
__device__ __forceinline__ float fdot2u(unsigned a, unsigned b, float c) {
    UH2 x, y; x.u = a; y.u = b;
    return __builtin_amdgcn_fdot2(x.h, y.h, c, false);
}
__device__ __forceinline__ float dot8(uint4 w, uint4 h, float acc) {
    acc = fdot2u(w.x, h.x, acc);
    acc = fdot2u(w.y, h.y, acc);
    acc = fdot2u(w.z, h.z, acc);
    acc = fdot2u(w.w, h.w, acc);
    return acc;
}

// pin a staged value into a VGPR: asm "modifies" it, so the register allocator
// cannot rematerialize it by re-loading from memory inside the step loop.
#define KEEPU4(v) asm volatile("" : "+v"((v).x), "+v"((v).y), "+v"((v).z), "+v"((v).w))

__device__ __forceinline__ float sigm(float x) { return 1.0f / (1.0f + expf(-x)); }

// ---- pack W_hh (1024x256 f32, rows = gate*256+j) into fp16 lane-major layout:
//   wph[(((s*4+g)*8 + k8)*256 + j)*8 + r] = (f16) W[g*256+j][s*64 + k8*8 + r]
// total elements = 4*4*8*256*8 = 262144
__global__ void k_packh(const float* __restrict__ w, _Float16* __restrict__ wph) {
    int e = blockIdx.x * 256 + threadIdx.x;     // 0..262143 (grid must be 1024 blocks)
    if (e >= 262144) return;
    int r  = e & 7;
    int j  = (e >> 3) & 255;
    int k8 = (e >> 11) & 7;
    int g  = (e >> 14) & 3;
    int s  = (e >> 16) & 3;
    wph[e] = (_Float16)w[(g * 256 + j) * HID + (s * 64 + k8 * 8 + r)];
}

// ---- char CNN: one block (128 thr) per word; conv k=3 pad=1 over L=16, maxpool
__global__ __launch_bounds__(128) void k_charcnn(const int* __restrict__ bchar,
                                                 const float* __restrict__ cemb,
                                                 const float* __restrict__ cw,
                                                 const float* __restrict__ cb,
                                                 float* __restrict__ pooled) {
    __shared__ float ET[DC][20];   // transposed emb with halo cols 0 and 17 = 0
    __shared__ int ids[LCH];
    int w = blockIdx.x;
    int tid = threadIdx.x;
    if (tid < LCH) ids[tid] = bchar[w * LCH + tid];
    __syncthreads();
    for (int s = tid; s < DC * 18; s += 128) {
        int d = s / 18, l = s % 18;
        float v = 0.f;
        if (l >= 1 && l <= 16) v = cemb[ids[l - 1] * DC + d];
        ET[d][l] = v;
    }
    __syncthreads();
    if (tid < CHN) {
        float acc[16];
#pragma unroll
        for (int l = 0; l < 16; l++) acc[l] = 0.f;
        for (int d = 0; d < DC; d++) {
            float e[18];
            float4 t0 = *(const float4*)&ET[d][0];
            float4 t1 = *(const float4*)&ET[d][4];
            float4 t2 = *(const float4*)&ET[d][8];
            float4 t3 = *(const float4*)&ET[d][12];
            e[0]=t0.x; e[1]=t0.y; e[2]=t0.z; e[3]=t0.w;
            e[4]=t1.x; e[5]=t1.y; e[6]=t1.z; e[7]=t1.w;
            e[8]=t2.x; e[9]=t2.y; e[10]=t2.z; e[11]=t2.w;
            e[12]=t3.x; e[13]=t3.y; e[14]=t3.z; e[15]=t3.w;
            e[16]=ET[d][16]; e[17]=ET[d][17];
            float w0 = cw[(tid * DC + d) * 3 + 0];
            float w1 = cw[(tid * DC + d) * 3 + 1];
            float w2 = cw[(tid * DC + d) * 3 + 2];
#pragma unroll
            for (int l = 0; l < 16; l++)
                acc[l] += w0 * e[l] + w1 * e[l + 1] + w2 * e[l + 2];
        }
        float m = acc[0];
#pragma unroll
        for (int l = 1; l < 16; l++) m = fmaxf(m, acc[l]);
        pooled[w * CHN + tid] = m + cb[tid];
    }
}

// ---- assemble x[16384][420] = [word_emb | char_feats(recovered) | feat_emb]
__global__ __launch_bounds__(128) void k_concat(const int* __restrict__ word,
                                                const int* __restrict__ featsidx,
                                                const int* __restrict__ recover,
                                                const float* __restrict__ wemb,
                                                const float* __restrict__ femb,
                                                const float* __restrict__ pooled,
                                                float* __restrict__ x) {
    int w = blockIdx.x;
    int tid = threadIdx.x;
    int b = w >> 8;
    int wid = word[w];
    for (int c = tid; c < DW; c += 128) x[(size_t)w * INDIM + c] = wemb[(size_t)wid * DW + c];
    int rc = recover[w];
    if (tid < CHN) x[(size_t)w * INDIM + DW + tid] = pooled[rc * CHN + tid];
    if (tid < DF)  x[(size_t)w * INDIM + DW + CHN + tid] = femb[featsidx[b] * DF + tid];
}

// ---- fp32 GEMM: C[m][g] = sum_k A[m][k]*W[g][k] + bias[g];  M=16384 N=1024 K=420
#define BM 128
#define BN 64
#define BK 16
__global__ __launch_bounds__(256) void k_gemm(const float* __restrict__ A,
                                              const float* __restrict__ Wt,
                                              const float* __restrict__ bias,
                                              float* __restrict__ C) {
    __shared__ float As[BK][BM];
    __shared__ float Bs[BK][BN];
    int tid = threadIdx.x;
    int tx = tid & 15, ty = tid >> 4;
    int m0 = blockIdx.y * BM, n0 = blockIdx.x * BN;
    float acc[8][4];
#pragma unroll
    for (int i = 0; i < 8; i++)
#pragma unroll
        for (int jj = 0; jj < 4; jj++) acc[i][jj] = 0.f;
    int am = tid >> 1, ak = (tid & 1) * 8;
    int bn = tid >> 2, bk = (tid & 3) * 4;
    for (int k0 = 0; k0 < INDIM; k0 += BK) {
#pragma unroll
        for (int q = 0; q < 8; q++) {
            int k = k0 + ak + q;
            As[ak + q][am] = (k < INDIM) ? A[(size_t)(m0 + am) * INDIM + k] : 0.f;
        }
#pragma unroll
        for (int q = 0; q < 4; q++) {
            int k = k0 + bk + q;
            Bs[bk + q][bn] = (k < INDIM) ? Wt[(size_t)(n0 + bn) * INDIM + k] : 0.f;
        }
        __syncthreads();
#pragma unroll
        for (int kk = 0; kk < BK; kk++) {
            float4 a0 = *(const float4*)&As[kk][ty * 8];
            float4 a1 = *(const float4*)&As[kk][ty * 8 + 4];
            float4 b0 = *(const float4*)&Bs[kk][tx * 4];
            float ra[8] = {a0.x, a0.y, a0.z, a0.w, a1.x, a1.y, a1.z, a1.w};
            float rb[4] = {b0.x, b0.y, b0.z, b0.w};
#pragma unroll
            for (int i = 0; i < 8; i++)
#pragma unroll
                for (int jj = 0; jj < 4; jj++) acc[i][jj] += ra[i] * rb[jj];
        }
        __syncthreads();
    }
    float4 bv = *(const float4*)&bias[n0 + tx * 4];
#pragma unroll
    for (int i = 0; i < 8; i++) {
        float4 o;
        o.x = acc[i][0] + bv.x; o.y = acc[i][1] + bv.y;
        o.z = acc[i][2] + bv.z; o.w = acc[i][3] + bv.w;
        *(float4*)&C[(size_t)(m0 + ty * 8 + i) * G4 + n0 + tx * 4] = o;
    }
}

// ---- masked BiLSTM: one 1024-thread block per (batch, dir); 128 blocks.
// CU-resident weights: gates i,f,g pinned in 96 VGPRs/thread (KEEPU4 defeats
// rematerialization); gate o in 128 KB LDS. x-row staged via 4 KB LDS
// (1 float/thread) to keep register pressure under the 128-VGPR cap.
__global__ __launch_bounds__(1024, 4) void k_lstm(const float* __restrict__ xs_f,
                                               const float* __restrict__ xs_b,
                                               const _Float16* __restrict__ wh_f,
                                               const _Float16* __restrict__ wh_b,
                                               const int* __restrict__ wlen,
                                               float* __restrict__ h_f,
                                               float* __restrict__ h_b) {
    int b = blockIdx.x & 63, d = blockIdx.x >> 6;
    const float* xs = d ? xs_b : xs_f;
    const uint4* wp4 = (const uint4*)(d ? wh_b : wh_f);
    float* ho = d ? h_b : h_f;
    int len = wlen[b];
    __shared__ uint4 olds4[8192];                 // o-gate weights, 128 KB
    __shared__ unsigned __align__(16) hh[128];    // f16x2-packed h state (256 units)
    __shared__ float part[4][4][256];             // [s][gate][unit], 16 KB
    __shared__ float xld[1024];                   // x-row staging, 4 KB
    int tid = threadIdx.x;
    int j = tid & 255, s = tid >> 8;
    // ---- stage weights: gates 0..2 -> registers, gate 3 -> LDS ----
    uint4 wr0[8], wr1[8], wr2[8];
    {
        const uint4* wq0 = wp4 + (size_t)((s * 4 + 0) * 8) * 256 + j;
        const uint4* wq1 = wp4 + (size_t)((s * 4 + 1) * 8) * 256 + j;
        const uint4* wq2 = wp4 + (size_t)((s * 4 + 2) * 8) * 256 + j;
        const uint4* wq3 = wp4 + (size_t)((s * 4 + 3) * 8) * 256 + j;
#pragma unroll
        for (int k8 = 0; k8 < 8; k8++) {
            wr0[k8] = wq0[k8 * 256];
            wr1[k8] = wq1[k8 * 256];
            wr2[k8] = wq2[k8 * 256];
            olds4[k8 * 1024 + tid] = wq3[k8 * 256];
        }
    }
#pragma unroll
    for (int k8 = 0; k8 < 8; k8++) {
        KEEPU4(wr0[k8]);
        KEEPU4(wr1[k8]);
        KEEPU4(wr2[k8]);
    }
    if (tid < 128) hh[tid] = 0u;
    float c0 = 0.f, c1 = 0.f;                     // epilogue cell states (2 units)
    const uint4* hsh4 = (const uint4*)hh;
    __syncthreads();
    for (int ss = 0; ss < len; ++ss) {
        int t = d ? (len - 1 - ss) : ss;
        // each thread loads exactly one float of the 1024-float x row
        float xv = xs[(size_t)(b * TT + t) * G4 + tid];
        float a0 = 0.f, a1 = 0.f, a2 = 0.f, a3 = 0.f;
#pragma unroll
        for (int k8 = 0; k8 < 8; k8++) {
            uint4 h4 = hsh4[s * 8 + k8];          // same-address broadcast within wave
            uint4 wo = olds4[k8 * 1024 + tid];    // stride-16B, conflict-free
            a0 = dot8(wr0[k8], h4, a0);
            a1 = dot8(wr1[k8], h4, a1);
            a2 = dot8(wr2[k8], h4, a2);
            a3 = dot8(wo, h4, a3);
        }
        part[s][0][j] = a0;
        part[s][1][j] = a1;
        part[s][2][j] = a2;
        part[s][3][j] = a3;
        xld[tid] = xv;
        __syncthreads();
        if (tid < 128) {
            float2 xv0 = *(const float2*)&xld[0 * 256 + 2 * tid];
            float2 xv1 = *(const float2*)&xld[1 * 256 + 2 * tid];
            float2 xv2 = *(const float2*)&xld[2 * 256 + 2 * tid];
            float2 xv3 = *(const float2*)&xld[3 * 256 + 2 * tid];
            float sum[4][2];
#pragma unroll
            for (int g = 0; g < 4; g++) {
                float2 p0 = *(const float2*)&part[0][g][2 * tid];
                float2 p1 = *(const float2*)&part[1][g][2 * tid];
                float2 p2 = *(const float2*)&part[2][g][2 * tid];
                float2 p3 = *(const float2*)&part[3][g][2 * tid];
                sum[g][0] = p0.x + p1.x + p2.x + p3.x;
                sum[g][1] = p0.y + p1.y + p2.y + p3.y;
            }
            sum[0][0] += xv0.x; sum[0][1] += xv0.y;
            sum[1][0] += xv1.x; sum[1][1] += xv1.y;
            sum[2][0] += xv2.x; sum[2][1] += xv2.y;
            sum[3][0] += xv3.x; sum[3][1] += xv3.y;
            float i0 = sigm(sum[0][0]), f0 = sigm(sum[1][0]);
            float z0 = tanhf(sum[2][0]), o0 = sigm(sum[3][0]);
            c0 = f0 * c0 + i0 * z0;
            float hA = o0 * tanhf(c0);
            float i1 = sigm(sum[0][1]), f1 = sigm(sum[1][1]);
            float z1 = tanhf(sum[2][1]), o1 = sigm(sum[3][1]);
            c1 = f1 * c1 + i1 * z1;
            float hB = o1 * tanhf(c1);
            UH2 pk;
            pk.h[0] = (_Float16)hA;
            pk.h[1] = (_Float16)hB;
            hh[tid] = pk.u;
            float2 st; st.x = hA; st.y = hB;
            *(float2*)&ho[(size_t)(b * TT + t) * HID + 2 * tid] = st;
        }
        __syncthreads();
    }
}

// ---- projection: feats[w][52] = [hf|hb] . proj_w[j] + proj_b[j]
__global__ __launch_bounds__(64) void k_proj(const float* __restrict__ hf,
                                             const float* __restrict__ hb,
                                             const float* __restrict__ pw,
                                             const float* __restrict__ pb,
                                             float* __restrict__ feats) {
    __shared__ float hc[512];
    int w = blockIdx.x;
    int tid = threadIdx.x;
    {
        float4 v = *(const float4*)&hf[(size_t)w * HID + tid * 4];
        *(float4*)&hc[tid * 4] = v;
        float4 u = *(const float4*)&hb[(size_t)w * HID + tid * 4];
        *(float4*)&hc[256 + tid * 4] = u;
    }
    __syncthreads();
    if (tid < NTAG) {
        float s = pb[tid];
        for (int k = 0; k < 512; k += 4) {
            float4 h4 = *(const float4*)&hc[k];
            float4 w4 = *(const float4*)&pw[(size_t)tid * 512 + k];
            s += h4.x * w4.x + h4.y * w4.y + h4.z * w4.z + h4.w * w4.w;
        }
        feats[(size_t)w * NTAG + tid] = s;
    }
}

// ---- CRF: forward (Z), gold score, viterbi + backtrace. one block per batch
__global__ __launch_bounds__(64) void k_crf(const float* __restrict__ feats,
                                            const float* __restrict__ trans,
                                            const int* __restrict__ wlen,
                                            const int* __restrict__ blabel,
                                            float* __restrict__ lossb,
                                            float* __restrict__ outtags) {
    __shared__ float Tm[NTAG * NTAG];
    __shared__ float alpha[NTAG], valpha[NTAG], frow[NTAG], red[NTAG];
    __shared__ unsigned char bp[TT - 1][NTAG];
    int b = blockIdx.x;
    int j = threadIdx.x;
    for (int s = j; s < NTAG * NTAG; s += 64) Tm[s] = trans[s];
    __syncthreads();
    int len = wlen[b];
    const float* fb = feats + (size_t)b * TT * NTAG;
    if (j < NTAG) {
        float a = fb[j] + Tm[TSTART * NTAG + j];
        alpha[j] = a;
        valpha[j] = a;
    }
    __syncthreads();
    for (int t = 1; t < len; t++) {
        if (j < NTAG) frow[j] = fb[(size_t)t * NTAG + j];
        __syncthreads();
        float anew = 0.f, vnew = 0.f;
        int arg = 0;
        if (j < NTAG) {
            float m1 = -1e30f;
            for (int i = 0; i < NTAG; i++) m1 = fmaxf(m1, alpha[i] + Tm[i * NTAG + j]);
            float ssum = 0.f;
            for (int i = 0; i < NTAG; i++) ssum += expf(alpha[i] + Tm[i * NTAG + j] - m1);
            anew = m1 + logf(ssum) + frow[j];
            float vm = -1e30f;
            for (int i = 0; i < NTAG; i++) {
                float sv = valpha[i] + Tm[i * NTAG + j];
                if (sv > vm) { vm = sv; arg = i; }   // strict > keeps first max (jnp.argmax)
            }
            vnew = vm + frow[j];
        }
        __syncthreads();
        if (j < NTAG) {
            alpha[j] = anew;
            valpha[j] = vnew;
            bp[t - 1][j] = (unsigned char)arg;
        }
        __syncthreads();
    }
    // ---- Z + gold (thread 0) ----
    if (j < NTAG) red[j] = alpha[j] + Tm[j * NTAG + TSTOP];
    __syncthreads();
    float Zg = 0.f, goldv = 0.f;
    if (j == 0) {
        float m1 = red[0];
        for (int i = 1; i < NTAG; i++) m1 = fmaxf(m1, red[i]);
        float ssum = 0.f;
        for (int i = 0; i < NTAG; i++) ssum += expf(red[i] - m1);
        Zg = m1 + logf(ssum);
        const int* lab = blabel + b * TT;
        goldv = Tm[TSTART * NTAG + lab[0]] + fb[lab[0]];
        for (int t = 1; t < len; t++)
            goldv += Tm[lab[t - 1] * NTAG + lab[t]] + fb[(size_t)t * NTAG + lab[t]];
        goldv += Tm[lab[len - 1] * NTAG + TSTOP];
    }
    __syncthreads();
    // ---- viterbi terminal + backtrace ----
    if (j < NTAG) red[j] = valpha[j] + Tm[j * NTAG + TSTOP];
    __syncthreads();
    if (j == 0) {
        int best = 0;
        float vm = red[0];
        for (int i = 1; i < NTAG; i++)
            if (red[i] > vm) { vm = red[i]; best = i; }
        float* ot = outtags + (size_t)b * TT;
        int tag = best;
        ot[len - 1] = (float)tag;
        for (int t = len - 2; t >= 0; t--) {
            tag = bp[t][tag];
            ot[t] = (float)tag;
        }
        for (int t = len; t < TT; t++) ot[t] = 0.f;
        lossb[b] = Zg - goldv;
    }
}

// ---- deterministic final loss reduction
__global__ void k_loss(const float* __restrict__ lossb, float* __restrict__ out) {
    if (threadIdx.x == 0 && blockIdx.x == 0) {
        float s = 0.f;
        for (int i = 0; i < BB; i++) s += lossb[i];
        out[0] = s;
    }
}

extern "C" void kernel_launch(void* const* d_in, const int* in_sizes, int n_in,
                              void* d_out, int out_size, void* d_ws, size_t ws_size,
                              hipStream_t stream) {
    const int* batch_word     = (const int*)d_in[0];
    const int* batch_features = (const int*)d_in[1];
    const int* batch_wordlen  = (const int*)d_in[2];
    const int* batch_char     = (const int*)d_in[3];
    const int* batch_recover  = (const int*)d_in[5];
    const int* batch_label    = (const int*)d_in[7];
    const float* char_emb = (const float*)d_in[8];
    const float* conv_w   = (const float*)d_in[9];
    const float* conv_b   = (const float*)d_in[10];
    const float* word_emb = (const float*)d_in[11];
    const float* feat_emb = (const float*)d_in[12];
    const float* w_ih_f   = (const float*)d_in[13];
    const float* w_hh_f   = (const float*)d_in[14];
    const float* b_f      = (const float*)d_in[15];
    const float* w_ih_b   = (const float*)d_in[16];
    const float* w_hh_b   = (const float*)d_in[17];
    const float* b_b      = (const float*)d_in[18];
    const float* proj_w   = (const float*)d_in[19];
    const float* proj_b   = (const float*)d_in[20];
    const float* trans    = (const float*)d_in[21];

    char* ws = (char*)d_ws;
    float* pooled = (float*)(ws + OFF_POOL);
    float* x      = (float*)(ws + OFF_X);
    float* h_f    = (float*)(ws + OFF_HF);
    float* h_b    = (float*)(ws + OFF_HB);
    float* xs_f   = (float*)(ws + OFF_XSF);
    float* xs_b   = (float*)(ws + OFF_XSB);
    float* feats  = (float*)(ws + OFF_FEATS);
    _Float16* wh_f = (_Float16*)(ws + OFF_WPF);
    _Float16* wh_b = (_Float16*)(ws + OFF_WPB);
    float* lossb  = (float*)(ws + OFF_LOSSB);

    k_packh<<<1024, 256, 0, stream>>>(w_hh_f, wh_f);
    k_packh<<<1024, 256, 0, stream>>>(w_hh_b, wh_b);
    k_charcnn<<<BB * TT, 128, 0, stream>>>(batch_char, char_emb, conv_w, conv_b, pooled);
    k_concat<<<BB * TT, 128, 0, stream>>>(batch_word, batch_features, batch_recover,
                                          word_emb, feat_emb, pooled, x);
    k_gemm<<<dim3(G4 / BN, (BB * TT) / BM), 256, 0, stream>>>(x, w_ih_f, b_f, xs_f);
    k_gemm<<<dim3(G4 / BN, (BB * TT) / BM), 256, 0, stream>>>(x, w_ih_b, b_b, xs_b);
    k_lstm<<<128, 1024, 0, stream>>>(xs_f, xs_b, wh_f, wh_b, batch_wordlen, h_f, h_b);
    k_proj<<<BB * TT, 64, 0, stream>>>(h_f, h_b, proj_w, proj_b, feats);
    k_crf<<<BB, 64, 0, stream>>>(feats, trans, batch_wordlen, batch_label,
                                 lossb, (float*)d_out + 1);
    k_loss<<<1, 64, 0, stream>>>(lossb, (float*)d_out);
}

// Round 8
// 2165.330 us; speedup vs baseline: 1.4314x; 1.4314x over previous
//
#include <hip/hip_runtime.h>
#include <hip/hip_bf16.h>
#include <math.h>

#define BB 64
#define TT 256
#define LCH 16
#define DC 50
#define CHN 100
#define DW 300
#define DF 20
#define HID 256
#define G4 1024
#define INDIM 420
#define KPAD 448
#define NTAG 52
#define TSTART 50
#define TSTOP 51

// ------------------- workspace layout (bytes) -------------------
// timeline: charcnn->pooled ; concat reads pooled, writes xh ; cvtw writes wh16
// (over dead pooled) ; gemm16 reads xh/wh16, writes xs ; lstm overwrites [0,33.5M)
// with h_f/h_b (xh/wh16 dead by then).
static constexpr size_t OFF_POOL  = 0;                       // 6,553,600 (dead after concat)
static constexpr size_t OFF_WH16F = 0;                       // 917,504 f16 (written after concat)
static constexpr size_t OFF_WH16B = 917504;                  // 917,504 -> 1,835,008
static constexpr size_t OFF_XH    = 6553600;                 // 14,680,064 f16 -> 21,233,664
static constexpr size_t OFF_HF    = 0;                       // 16,777,216 (lstm output)
static constexpr size_t OFF_HB    = 16777216;                // 16,777,216 -> 33,554,432
static constexpr size_t OFF_XSF   = 34078720;                // 67,108,864
static constexpr size_t OFF_XSB   = 101187584;               // 67,108,864 -> 168,296,448
static constexpr size_t OFF_FEATS = 168296448;               // 3,407,872  -> 171,704,320
static constexpr size_t OFF_WPF   = 171704320;               // 512 KB (fp16 packed W_hh fwd)
static constexpr size_t OFF_WPB   = 172752896;               // 512 KB (fp16 packed W_hh bwd)
static constexpr size_t OFF_LOSSB = 173801472;               // 256

typedef _Float16 v2h __attribute__((ext_vector_type(2)));
typedef _Float16 f16x8 __attribute__((ext_vector_type(8)));
typedef float f32x4 __attribute__((ext_vector_type(4)));
union UH2 { unsigned u; v2h h; };
__device__ __forceinline__ float fdot2u(unsigned a, unsigned b, float c) {
    UH2 x, y; x.u = a; y.u = b;
    return __builtin_amdgcn_fdot2(x.h, y.h, c, false);
}
__device__ __forceinline__ float dot8(uint4 w, uint4 h, float acc) {
    acc = fdot2u(w.x, h.x, acc);
    acc = fdot2u(w.y, h.y, acc);
    acc = fdot2u(w.z, h.z, acc);
    acc = fdot2u(w.w, h.w, acc);
    return acc;
}

// pin a staged value into a VGPR (asm may have modified it -> no remat/reload)
#define KEEPU4(v) asm volatile("" : "+v"((v).x), "+v"((v).y), "+v"((v).z), "+v"((v).w))

__device__ __forceinline__ float sigm(float x) { return 1.0f / (1.0f + expf(-x)); }

// ---- pack W_hh (1024x256 f32, rows = gate*256+j) into fp16 lane-major layout:
//   wph[(((s*4+g)*8 + k8)*256 + j)*8 + r] = (f16) W[g*256+j][s*64 + k8*8 + r]
__global__ void k_packh(const float* __restrict__ w, _Float16* __restrict__ wph) {
    int e = blockIdx.x * 256 + threadIdx.x;     // 0..262143 (grid 1024 blocks)
    if (e >= 262144) return;
    int r  = e & 7;
    int j  = (e >> 3) & 255;
    int k8 = (e >> 11) & 7;
    int g  = (e >> 14) & 3;
    int s  = (e >> 16) & 3;
    wph[e] = (_Float16)w[(g * 256 + j) * HID + (s * 64 + k8 * 8 + r)];
}

// ---- convert w_ih [1024][420] f32 -> [1024][448] f16 (zero-padded K)
__global__ void k_cvtw(const float* __restrict__ w, _Float16* __restrict__ wh) {
    int e = blockIdx.x * 256 + threadIdx.x;     // grid 1792 -> 458752
    if (e >= G4 * KPAD) return;
    int row = e / KPAD, k = e % KPAD;
    wh[e] = (k < INDIM) ? (_Float16)w[row * INDIM + k] : (_Float16)0.f;
}

// ---- char CNN: one block (128 thr) per word; conv k=3 pad=1 over L=16, maxpool
__global__ __launch_bounds__(128) void k_charcnn(const int* __restrict__ bchar,
                                                 const float* __restrict__ cemb,
                                                 const float* __restrict__ cw,
                                                 const float* __restrict__ cb,
                                                 float* __restrict__ pooled) {
    __shared__ float ET[DC][20];
    __shared__ int ids[LCH];
    int w = blockIdx.x;
    int tid = threadIdx.x;
    if (tid < LCH) ids[tid] = bchar[w * LCH + tid];
    __syncthreads();
    for (int s = tid; s < DC * 18; s += 128) {
        int d = s / 18, l = s % 18;
        float v = 0.f;
        if (l >= 1 && l <= 16) v = cemb[ids[l - 1] * DC + d];
        ET[d][l] = v;
    }
    __syncthreads();
    if (tid < CHN) {
        float acc[16];
#pragma unroll
        for (int l = 0; l < 16; l++) acc[l] = 0.f;
        for (int d = 0; d < DC; d++) {
            float e[18];
            float4 t0 = *(const float4*)&ET[d][0];
            float4 t1 = *(const float4*)&ET[d][4];
            float4 t2 = *(const float4*)&ET[d][8];
            float4 t3 = *(const float4*)&ET[d][12];
            e[0]=t0.x; e[1]=t0.y; e[2]=t0.z; e[3]=t0.w;
            e[4]=t1.x; e[5]=t1.y; e[6]=t1.z; e[7]=t1.w;
            e[8]=t2.x; e[9]=t2.y; e[10]=t2.z; e[11]=t2.w;
            e[12]=t3.x; e[13]=t3.y; e[14]=t3.z; e[15]=t3.w;
            e[16]=ET[d][16]; e[17]=ET[d][17];
            float w0 = cw[(tid * DC + d) * 3 + 0];
            float w1 = cw[(tid * DC + d) * 3 + 1];
            float w2 = cw[(tid * DC + d) * 3 + 2];
#pragma unroll
            for (int l = 0; l < 16; l++)
                acc[l] += w0 * e[l] + w1 * e[l + 1] + w2 * e[l + 2];
        }
        float m = acc[0];
#pragma unroll
        for (int l = 1; l < 16; l++) m = fmaxf(m, acc[l]);
        pooled[w * CHN + tid] = m + cb[tid];
    }
}

// ---- assemble xh[16384][448] f16 = [word_emb | char_feats | feat_emb | 0-pad]
__global__ __launch_bounds__(128) void k_concat(const int* __restrict__ word,
                                                const int* __restrict__ featsidx,
                                                const int* __restrict__ recover,
                                                const float* __restrict__ wemb,
                                                const float* __restrict__ femb,
                                                const float* __restrict__ pooled,
                                                _Float16* __restrict__ xh) {
    int w = blockIdx.x;
    int tid = threadIdx.x;
    int b = w >> 8;
    int wid = word[w];
    _Float16* xr = xh + (size_t)w * KPAD;
    for (int c = tid; c < DW; c += 128) xr[c] = (_Float16)wemb[(size_t)wid * DW + c];
    int rc = recover[w];
    if (tid < CHN) xr[DW + tid] = (_Float16)pooled[rc * CHN + tid];
    if (tid < DF)  xr[DW + CHN + tid] = (_Float16)femb[featsidx[b] * DF + tid];
    if (tid >= 100 && tid < 100 + (KPAD - INDIM)) xr[INDIM + (tid - 100)] = (_Float16)0.f;
}

// ---- f16 MFMA GEMM: xs[m][n] = sum_k xh[m][k]*wh[n][k] + bias[n]
// block 256 thr = 4 waves; block tile 64(m) x 64(n); wave wv: rows [wv*16, wv*16+16)
// x all 64 n (4 n-frags, a reused). Frags read straight from global (L2-resident B).
__global__ __launch_bounds__(256) void k_gemm16(const _Float16* __restrict__ A,
                                                const _Float16* __restrict__ Bw,
                                                const float* __restrict__ bias,
                                                float* __restrict__ C) {
    int tid = threadIdx.x;
    int wv = tid >> 6, l = tid & 63;
    int lm = l & 15, lk = l >> 4;
    int n0 = blockIdx.x * 64, m0 = blockIdx.y * 64;
    const _Float16* ap = A + (size_t)(m0 + wv * 16 + lm) * KPAD + lk * 8;
    const _Float16* b0 = Bw + (size_t)(n0 + 0 * 16 + lm) * KPAD + lk * 8;
    const _Float16* b1 = Bw + (size_t)(n0 + 1 * 16 + lm) * KPAD + lk * 8;
    const _Float16* b2 = Bw + (size_t)(n0 + 2 * 16 + lm) * KPAD + lk * 8;
    const _Float16* b3 = Bw + (size_t)(n0 + 3 * 16 + lm) * KPAD + lk * 8;
    f32x4 ac0 = {0.f, 0.f, 0.f, 0.f}, ac1 = ac0, ac2 = ac0, ac3 = ac0;
    for (int k0 = 0; k0 < KPAD; k0 += 32) {
        f16x8 a  = *(const f16x8*)(ap + k0);
        f16x8 v0 = *(const f16x8*)(b0 + k0);
        f16x8 v1 = *(const f16x8*)(b1 + k0);
        f16x8 v2 = *(const f16x8*)(b2 + k0);
        f16x8 v3 = *(const f16x8*)(b3 + k0);
        ac0 = __builtin_amdgcn_mfma_f32_16x16x32_f16(a, v0, ac0, 0, 0, 0);
        ac1 = __builtin_amdgcn_mfma_f32_16x16x32_f16(a, v1, ac1, 0, 0, 0);
        ac2 = __builtin_amdgcn_mfma_f32_16x16x32_f16(a, v2, ac2, 0, 0, 0);
        ac3 = __builtin_amdgcn_mfma_f32_16x16x32_f16(a, v3, ac3, 0, 0, 0);
    }
    int orow = m0 + wv * 16 + lk * 4;        // C/D: col=lane&15, row=(lane>>4)*4+r
    f32x4 accs[4] = {ac0, ac1, ac2, ac3};
#pragma unroll
    for (int jn = 0; jn < 4; jn++) {
        int col = n0 + jn * 16 + lm;
        float bv = bias[col];
#pragma unroll
        for (int r = 0; r < 4; r++)
            C[(size_t)(orow + r) * G4 + col] = accs[jn][r] + bv;
    }
}

// ---- masked BiLSTM: one 1024-thread block per (batch, dir); 128 blocks.
// o-gate in 128 KB LDS; g-gate pinned in 32 VGPRs (fits the 64-reg budget);
// i,f streamed from L2 each step via laundered pointers (256 KB/step).
__global__ __launch_bounds__(1024, 4) void k_lstm(const float* __restrict__ xs_f,
                                               const float* __restrict__ xs_b,
                                               const _Float16* __restrict__ wh_f,
                                               const _Float16* __restrict__ wh_b,
                                               const int* __restrict__ wlen,
                                               float* __restrict__ h_f,
                                               float* __restrict__ h_b) {
    int b = blockIdx.x & 63, d = blockIdx.x >> 6;
    const float* xs = d ? xs_b : xs_f;
    const uint4* wp4 = (const uint4*)(d ? wh_b : wh_f);
    float* ho = d ? h_b : h_f;
    int len = wlen[b];
    __shared__ uint4 olds4[8192];                 // o-gate weights, 128 KB
    __shared__ unsigned __align__(16) hh[128];    // f16x2-packed h state
    __shared__ float part[4][4][256];             // [s][gate][unit], 16 KB
    int tid = threadIdx.x;
    int j = tid & 255, s = tid >> 8;
    const uint4* pi = wp4 + (size_t)((s * 4 + 0) * 8) * 256 + j;   // i-gate (streamed)
    const uint4* pf = wp4 + (size_t)((s * 4 + 1) * 8) * 256 + j;   // f-gate (streamed)
    uint4 wg[8];                                   // g-gate resident
    {
        const uint4* pg = wp4 + (size_t)((s * 4 + 2) * 8) * 256 + j;
        const uint4* po = wp4 + (size_t)((s * 4 + 3) * 8) * 256 + j;
#pragma unroll
        for (int k8 = 0; k8 < 8; k8++) {
            wg[k8] = pg[k8 * 256];
            olds4[k8 * 1024 + tid] = po[k8 * 256];
        }
    }
#pragma unroll
    for (int k8 = 0; k8 < 8; k8++) KEEPU4(wg[k8]);
    if (tid < 128) hh[tid] = 0u;
    float c0 = 0.f, c1 = 0.f;
    const uint4* hsh4 = (const uint4*)hh;
    __syncthreads();
    for (int ss = 0; ss < len; ++ss) {
        int t = d ? (len - 1 - ss) : ss;
        float2 xv0, xv1, xv2, xv3;
        if (tid < 128) {
            const float2* xr2 = (const float2*)(xs + (size_t)(b * TT + t) * G4);
            xv0 = xr2[0 * 128 + tid];
            xv1 = xr2[1 * 128 + tid];
            xv2 = xr2[2 * 128 + tid];
            xv3 = xr2[3 * 128 + tid];
        }
        // launder the stream pointers so i/f loads re-issue each step (no hoist)
        asm volatile("" : "+v"(pi), "+v"(pf));
        float a0 = 0.f, a1 = 0.f, a2 = 0.f, a3 = 0.f;
#pragma unroll
        for (int k8 = 0; k8 < 8; k8++) {
            uint4 h4 = hsh4[s * 8 + k8];          // same-address broadcast
            uint4 wi = pi[k8 * 256];
            uint4 wf = pf[k8 * 256];
            uint4 wo = olds4[k8 * 1024 + tid];
            a0 = dot8(wi, h4, a0);
            a1 = dot8(wf, h4, a1);
            a2 = dot8(wg[k8], h4, a2);
            a3 = dot8(wo, h4, a3);
        }
        part[s][0][j] = a0;
        part[s][1][j] = a1;
        part[s][2][j] = a2;
        part[s][3][j] = a3;
        __syncthreads();
        if (tid < 128) {
            float sum[4][2];
#pragma unroll
            for (int g = 0; g < 4; g++) {
                float2 p0 = *(const float2*)&part[0][g][2 * tid];
                float2 p1 = *(const float2*)&part[1][g][2 * tid];
                float2 p2 = *(const float2*)&part[2][g][2 * tid];
                float2 p3 = *(const float2*)&part[3][g][2 * tid];
                sum[g][0] = p0.x + p1.x + p2.x + p3.x;
                sum[g][1] = p0.y + p1.y + p2.y + p3.y;
            }
            sum[0][0] += xv0.x; sum[0][1] += xv0.y;
            sum[1][0] += xv1.x; sum[1][1] += xv1.y;
            sum[2][0] += xv2.x; sum[2][1] += xv2.y;
            sum[3][0] += xv3.x; sum[3][1] += xv3.y;
            float i0 = sigm(sum[0][0]), f0 = sigm(sum[1][0]);
            float z0 = tanhf(sum[2][0]), o0 = sigm(sum[3][0]);
            c0 = f0 * c0 + i0 * z0;
            float hA = o0 * tanhf(c0);
            float i1 = sigm(sum[0][1]), f1 = sigm(sum[1][1]);
            float z1 = tanhf(sum[2][1]), o1 = sigm(sum[3][1]);
            c1 = f1 * c1 + i1 * z1;
            float hB = o1 * tanhf(c1);
            UH2 pk;
            pk.h[0] = (_Float16)hA;
            pk.h[1] = (_Float16)hB;
            hh[tid] = pk.u;
            float2 st; st.x = hA; st.y = hB;
            *(float2*)&ho[(size_t)(b * TT + t) * HID + 2 * tid] = st;
        }
        __syncthreads();
    }
}

// ---- projection: proj_w LDS-resident (stride-513 pad), 64 words per block
__global__ __launch_bounds__(256) void k_proj(const float* __restrict__ hf,
                                              const float* __restrict__ hb,
                                              const float* __restrict__ pw,
                                              const float* __restrict__ pb,
                                              float* __restrict__ feats) {
    __shared__ float pwsh[NTAG][513];
    __shared__ float hsh[512];
    __shared__ float part2[4][NTAG];
    int tid = threadIdx.x;
    int w0 = blockIdx.x * 64;
    for (int i = tid; i < NTAG * 512; i += 256) pwsh[i >> 9][i & 511] = pw[i];
    __syncthreads();
    int q = tid >> 6, t = tid & 63;
    for (int wi = 0; wi < 64; wi++) {
        int w = w0 + wi;
        hsh[tid]       = hf[(size_t)w * HID + tid];
        hsh[256 + tid] = hb[(size_t)w * HID + tid];
        __syncthreads();
        if (t < NTAG) {
            float ssum = 0.f;
            int k0 = q * 128;
            for (int k = 0; k < 128; k++) ssum += pwsh[t][k0 + k] * hsh[k0 + k];
            part2[q][t] = ssum;
        }
        __syncthreads();
        if (tid < NTAG)
            feats[(size_t)w * NTAG + tid] =
                part2[0][tid] + part2[1][tid] + part2[2][tid] + part2[3][tid] + pb[tid];
        __syncthreads();
    }
}

// ---- CRF: forward (Z), gold score, viterbi + backtrace. one block per batch
__global__ __launch_bounds__(64) void k_crf(const float* __restrict__ feats,
                                            const float* __restrict__ trans,
                                            const int* __restrict__ wlen,
                                            const int* __restrict__ blabel,
                                            float* __restrict__ lossb,
                                            float* __restrict__ outtags) {
    __shared__ float Tm[NTAG * NTAG];
    __shared__ float alpha[NTAG], valpha[NTAG], frow[NTAG], red[NTAG];
    __shared__ unsigned char bp[TT - 1][NTAG];
    int b = blockIdx.x;
    int j = threadIdx.x;
    for (int s = j; s < NTAG * NTAG; s += 64) Tm[s] = trans[s];
    __syncthreads();
    int len = wlen[b];
    const float* fb = feats + (size_t)b * TT * NTAG;
    if (j < NTAG) {
        float a = fb[j] + Tm[TSTART * NTAG + j];
        alpha[j] = a;
        valpha[j] = a;
    }
    __syncthreads();
    for (int t = 1; t < len; t++) {
        if (j < NTAG) frow[j] = fb[(size_t)t * NTAG + j];
        __syncthreads();
        float anew = 0.f, vnew = 0.f;
        int arg = 0;
        if (j < NTAG) {
            float m1 = -1e30f;
            for (int i = 0; i < NTAG; i++) m1 = fmaxf(m1, alpha[i] + Tm[i * NTAG + j]);
            float ssum = 0.f;
            for (int i = 0; i < NTAG; i++) ssum += expf(alpha[i] + Tm[i * NTAG + j] - m1);
            anew = m1 + logf(ssum) + frow[j];
            float vm = -1e30f;
            for (int i = 0; i < NTAG; i++) {
                float sv = valpha[i] + Tm[i * NTAG + j];
                if (sv > vm) { vm = sv; arg = i; }   // strict > = first max (jnp.argmax)
            }
            vnew = vm + frow[j];
        }
        __syncthreads();
        if (j < NTAG) {
            alpha[j] = anew;
            valpha[j] = vnew;
            bp[t - 1][j] = (unsigned char)arg;
        }
        __syncthreads();
    }
    if (j < NTAG) red[j] = alpha[j] + Tm[j * NTAG + TSTOP];
    __syncthreads();
    float Zg = 0.f, goldv = 0.f;
    if (j == 0) {
        float m1 = red[0];
        for (int i = 1; i < NTAG; i++) m1 = fmaxf(m1, red[i]);
        float ssum = 0.f;
        for (int i = 0; i < NTAG; i++) ssum += expf(red[i] - m1);
        Zg = m1 + logf(ssum);
        const int* lab = blabel + b * TT;
        goldv = Tm[TSTART * NTAG + lab[0]] + fb[lab[0]];
        for (int t = 1; t < len; t++)
            goldv += Tm[lab[t - 1] * NTAG + lab[t]] + fb[(size_t)t * NTAG + lab[t]];
        goldv += Tm[lab[len - 1] * NTAG + TSTOP];
    }
    __syncthreads();
    if (j < NTAG) red[j] = valpha[j] + Tm[j * NTAG + TSTOP];
    __syncthreads();
    if (j == 0) {
        int best = 0;
        float vm = red[0];
        for (int i = 1; i < NTAG; i++)
            if (red[i] > vm) { vm = red[i]; best = i; }
        float* ot = outtags + (size_t)b * TT;
        int tag = best;
        ot[len - 1] = (float)tag;
        for (int t = len - 2; t >= 0; t--) {
            tag = bp[t][tag];
            ot[t] = (float)tag;
        }
        for (int t = len; t < TT; t++) ot[t] = 0.f;
        lossb[b] = Zg - goldv;
    }
}

// ---- deterministic final loss reduction
__global__ void k_loss(const float* __restrict__ lossb, float* __restrict__ out) {
    if (threadIdx.x == 0 && blockIdx.x == 0) {
        float s = 0.f;
        for (int i = 0; i < BB; i++) s += lossb[i];
        out[0] = s;
    }
}

extern "C" void kernel_launch(void* const* d_in, const int* in_sizes, int n_in,
                              void* d_out, int out_size, void* d_ws, size_t ws_size,
                              hipStream_t stream) {
    const int* batch_word     = (const int*)d_in[0];
    const int* batch_features = (const int*)d_in[1];
    const int* batch_wordlen  = (const int*)d_in[2];
    const int* batch_char     = (const int*)d_in[3];
    const int* batch_recover  = (const int*)d_in[5];
    const int* batch_label    = (const int*)d_in[7];
    const float* char_emb = (const float*)d_in[8];
    const float* conv_w   = (const float*)d_in[9];
    const float* conv_b   = (const float*)d_in[10];
    const float* word_emb = (const float*)d_in[11];
    const float* feat_emb = (const float*)d_in[12];
    const float* w_ih_f   = (const float*)d_in[13];
    const float* w_hh_f   = (const float*)d_in[14];
    const float* b_f      = (const float*)d_in[15];
    const float* w_ih_b   = (const float*)d_in[16];
    const float* w_hh_b   = (const float*)d_in[17];
    const float* b_b      = (const float*)d_in[18];
    const float* proj_w   = (const float*)d_in[19];
    const float* proj_b   = (const float*)d_in[20];
    const float* trans    = (const float*)d_in[21];

    char* ws = (char*)d_ws;
    float* pooled   = (float*)(ws + OFF_POOL);
    _Float16* wh16f = (_Float16*)(ws + OFF_WH16F);
    _Float16* wh16b = (_Float16*)(ws + OFF_WH16B);
    _Float16* xh    = (_Float16*)(ws + OFF_XH);
    float* h_f    = (float*)(ws + OFF_HF);
    float* h_b    = (float*)(ws + OFF_HB);
    float* xs_f   = (float*)(ws + OFF_XSF);
    float* xs_b   = (float*)(ws + OFF_XSB);
    float* feats  = (float*)(ws + OFF_FEATS);
    _Float16* wh_f = (_Float16*)(ws + OFF_WPF);
    _Float16* wh_b = (_Float16*)(ws + OFF_WPB);
    float* lossb  = (float*)(ws + OFF_LOSSB);

    k_packh<<<1024, 256, 0, stream>>>(w_hh_f, wh_f);
    k_packh<<<1024, 256, 0, stream>>>(w_hh_b, wh_b);
    k_charcnn<<<BB * TT, 128, 0, stream>>>(batch_char, char_emb, conv_w, conv_b, pooled);
    k_concat<<<BB * TT, 128, 0, stream>>>(batch_word, batch_features, batch_recover,
                                          word_emb, feat_emb, pooled, xh);
    // pooled dead now -> wh16 conversions may overwrite that region
    k_cvtw<<<1792, 256, 0, stream>>>(w_ih_f, wh16f);
    k_cvtw<<<1792, 256, 0, stream>>>(w_ih_b, wh16b);
    k_gemm16<<<dim3(G4 / 64, (BB * TT) / 64), 256, 0, stream>>>(xh, wh16f, b_f, xs_f);
    k_gemm16<<<dim3(G4 / 64, (BB * TT) / 64), 256, 0, stream>>>(xh, wh16b, b_b, xs_b);
    k_lstm<<<128, 1024, 0, stream>>>(xs_f, xs_b, wh_f, wh_b, batch_wordlen, h_f, h_b);
    k_proj<<<(BB * TT) / 64, 256, 0, stream>>>(h_f, h_b, proj_w, proj_b, feats);
    k_crf<<<BB, 64, 0, stream>>>(feats, trans, batch_wordlen, batch_label,
                                 lossb, (float*)d_out + 1);
    k_loss<<<1, 64, 0, stream>>>(lossb, (float*)d_out);
}